// Round 1
// baseline (403.063 us; speedup 1.0000x reference)
//
#include <hip/hip_runtime.h>
#include <hip/hip_bf16.h>

// Shapes (fixed by the problem): B=4, H=56, W=56, C=256, NH=8, HD=32, KS=7, PAD=3
// tokens M = 4*56*56 = 12544 (divisible by 64), QKV N = 768, proj N = 256, K = 256.

#define BM 64
#define BN 64
#define BK 16

// C[M,N] = A[M,K] @ B[K,N] + bias[N]; columns < qcols additionally scaled by qscale.
__global__ __launch_bounds__(256) void gemm_bias(
    const float* __restrict__ A, const float* __restrict__ B,
    const float* __restrict__ bias, float* __restrict__ C,
    int M, int N, int K, float qscale, int qcols)
{
    __shared__ float As[BK][BM + 1];   // A tile, transposed: As[k][m]
    __shared__ float Bs[BK][BN];       // B tile: Bs[k][n]

    const int tid = threadIdx.x;
    const int m0 = blockIdx.y * BM;
    const int n0 = blockIdx.x * BN;
    const int tx = tid & 15;           // 16 col-groups
    const int ty = tid >> 4;           // 16 row-groups

    float acc[4][4] = {};

    for (int k0 = 0; k0 < K; k0 += BK) {
        // Load A tile (64 rows x 16 k) via float4: thread -> row tid>>2, kquad tid&3
        {
            const int m  = tid >> 2;
            const int kq = (tid & 3) * 4;
            const float4 av = *(const float4*)(A + (size_t)(m0 + m) * K + k0 + kq);
            As[kq + 0][m] = av.x; As[kq + 1][m] = av.y;
            As[kq + 2][m] = av.z; As[kq + 3][m] = av.w;
        }
        // Load B tile (16 k x 64 n) via float4: thread -> k tid>>4, nquad tid&15
        {
            const int k  = tid >> 4;
            const int nq = (tid & 15) * 4;
            *(float4*)(&Bs[k][nq]) = *(const float4*)(B + (size_t)(k0 + k) * N + n0 + nq);
        }
        __syncthreads();

        #pragma unroll
        for (int k = 0; k < BK; ++k) {
            float ra[4], rb[4];
            #pragma unroll
            for (int i = 0; i < 4; ++i) ra[i] = As[k][ty * 4 + i];
            #pragma unroll
            for (int j = 0; j < 4; ++j) rb[j] = Bs[k][tx * 4 + j];
            #pragma unroll
            for (int i = 0; i < 4; ++i)
                #pragma unroll
                for (int j = 0; j < 4; ++j)
                    acc[i][j] += ra[i] * rb[j];
        }
        __syncthreads();
    }

    // Epilogue: bias, optional q-scale, store
    #pragma unroll
    for (int i = 0; i < 4; ++i) {
        const int m = m0 + ty * 4 + i;
        #pragma unroll
        for (int j = 0; j < 4; ++j) {
            const int n = n0 + tx * 4 + j;
            float v = acc[i][j] + bias[n];
            if (n < qcols) v *= qscale;
            C[(size_t)m * N + n] = v;
        }
    }
}

// One block per token; 256 threads = 8 heads x 32 channels.
// qkv layout: [token][768] where [0:256)=q (pre-scaled), [256:512)=k, [512:768)=v.
// OOB neighbors: k=v=0 (zero padding) -> logit = rpb only, still in softmax.
__global__ __launch_bounds__(256) void na2d_attn(
    const float* __restrict__ qkv, const float* __restrict__ rpb,
    float* __restrict__ out)
{
    const int t   = blockIdx.x;              // 0..12543
    const int b   = t / (56 * 56);
    const int rem = t % (56 * 56);
    const int y   = rem / 56;
    const int x   = rem % 56;

    const int c    = threadIdx.x;            // 0..255 channel
    const int head = c >> 5;                 // 0..7
    const int lane = c & 31;                 // 0..31

    __shared__ float p[8][49];               // logits -> probs per head

    const float qc = qkv[(size_t)t * 768 + c];   // q, already scaled

    // ---- logits: dot(q_head, k_head) per neighbor, segmented 32-lane reduce ----
    #pragma unroll 7
    for (int kk = 0; kk < 49; ++kk) {
        const int yy = y + kk / 7 - 3;
        const int xx = x + kk % 7 - 3;
        float kv = 0.f;
        if (yy >= 0 && yy < 56 && xx >= 0 && xx < 56)
            kv = qkv[((size_t)((b * 56 + yy) * 56 + xx)) * 768 + 256 + c];
        float prod = qc * kv;
        prod += __shfl_down(prod, 16, 32);
        prod += __shfl_down(prod, 8, 32);
        prod += __shfl_down(prod, 4, 32);
        prod += __shfl_down(prod, 2, 32);
        prod += __shfl_down(prod, 1, 32);
        if (lane == 0) p[head][kk] = prod;
    }
    __syncthreads();

    // ---- softmax over 49 (+rpb, incl. OOB positions) with 32 lanes per head ----
    {
        float l0 = (lane < 49)      ? p[head][lane]      + rpb[head * 49 + lane]      : -1e30f;
        float l1 = (lane + 32 < 49) ? p[head][lane + 32] + rpb[head * 49 + lane + 32] : -1e30f;
        float mx = fmaxf(l0, l1);
        #pragma unroll
        for (int off = 16; off; off >>= 1) mx = fmaxf(mx, __shfl_xor(mx, off, 32));
        const float e0 = (lane < 49)      ? __expf(l0 - mx) : 0.f;
        const float e1 = (lane + 32 < 49) ? __expf(l1 - mx) : 0.f;
        float s = e0 + e1;
        #pragma unroll
        for (int off = 16; off; off >>= 1) s += __shfl_xor(s, off, 32);
        const float inv = 1.f / s;
        __syncthreads();  // all reads of logits done before overwrite
        if (lane < 49)      p[head][lane]      = e0 * inv;
        if (lane + 32 < 49) p[head][lane + 32] = e1 * inv;
    }
    __syncthreads();

    // ---- output: coalesced v reads, prob broadcast from LDS ----
    float acc = 0.f;
    #pragma unroll 7
    for (int kk = 0; kk < 49; ++kk) {
        const int yy = y + kk / 7 - 3;
        const int xx = x + kk % 7 - 3;
        if (yy >= 0 && yy < 56 && xx >= 0 && xx < 56) {
            const float vv = qkv[((size_t)((b * 56 + yy) * 56 + xx)) * 768 + 512 + c];
            acc += p[head][kk] * vv;
        }
    }
    out[(size_t)t * 256 + c] = acc;
}

extern "C" void kernel_launch(void* const* d_in, const int* in_sizes, int n_in,
                              void* d_out, int out_size, void* d_ws, size_t ws_size,
                              hipStream_t stream)
{
    const float* x      = (const float*)d_in[0];   // (4,56,56,256)
    const float* w_qkv  = (const float*)d_in[1];   // (256,768)
    const float* b_qkv  = (const float*)d_in[2];   // (768,)
    const float* rpb    = (const float*)d_in[3];   // (8,49)
    const float* w_proj = (const float*)d_in[4];   // (256,256)
    const float* b_proj = (const float*)d_in[5];   // (256,)
    float* out = (float*)d_out;                    // (4,56,56,256) fp32

    const int M = 12544;                           // 4*56*56
    float* qkv      = (float*)d_ws;                // M*768 floats = 38.5 MB
    float* attn_out = qkv + (size_t)M * 768;       // M*256 floats = 12.8 MB

    const float scale = 0.17677669529663689f;      // 32^-0.5

    // qkv = x @ w_qkv + b_qkv, q columns pre-scaled
    gemm_bias<<<dim3(768 / BN, M / BM), 256, 0, stream>>>(
        x, w_qkv, b_qkv, qkv, M, 768, 256, scale, 256);

    // neighborhood attention
    na2d_attn<<<M, 256, 0, stream>>>(qkv, rpb, attn_out);

    // out = attn_out @ w_proj + b_proj
    gemm_bias<<<dim3(256 / BN, M / BM), 256, 0, stream>>>(
        attn_out, w_proj, b_proj, out, M, 256, 256, 1.f, 0);
}

// Round 2
// 366.445 us; speedup vs baseline: 1.0999x; 1.0999x over previous
//
#include <hip/hip_runtime.h>
#include <hip/hip_bf16.h>

// Shapes (fixed): B=4, H=56, W=56, C=256, NH=8, HD=32, KS=7, PAD=3
// tokens M = 4*56*56 = 12544, QKV N = 768, proj N = 256, K = 256.

#define BM 64
#define BN 64
#define BK 16

// C[M,N] = A[M,K] @ B[K,N] + bias[N]; columns < qcols additionally scaled by qscale.
__global__ __launch_bounds__(256) void gemm_bias(
    const float* __restrict__ A, const float* __restrict__ B,
    const float* __restrict__ bias, float* __restrict__ C,
    int M, int N, int K, float qscale, int qcols)
{
    // +4 pad: row stride 68 floats = 272 B (16B-aligned) -> float4 LDS reads.
    __shared__ float As[BK][BM + 4];   // A tile, transposed: As[k][m]
    __shared__ float Bs[BK][BN];       // B tile: Bs[k][n]

    const int tid = threadIdx.x;
    const int m0 = blockIdx.y * BM;
    const int n0 = blockIdx.x * BN;
    const int tx = tid & 15;           // 16 col-groups
    const int ty = tid >> 4;           // 16 row-groups

    float acc[4][4] = {};

    for (int k0 = 0; k0 < K; k0 += BK) {
        // Load A tile (64 rows x 16 k) via float4: thread -> row tid>>2, kquad tid&3
        {
            const int m  = tid >> 2;
            const int kq = (tid & 3) * 4;
            const float4 av = *(const float4*)(A + (size_t)(m0 + m) * K + k0 + kq);
            As[kq + 0][m] = av.x; As[kq + 1][m] = av.y;
            As[kq + 2][m] = av.z; As[kq + 3][m] = av.w;
        }
        // Load B tile (16 k x 64 n) via float4: thread -> k tid>>4, nquad tid&15
        {
            const int k  = tid >> 4;
            const int nq = (tid & 15) * 4;
            *(float4*)(&Bs[k][nq]) = *(const float4*)(B + (size_t)(k0 + k) * N + n0 + nq);
        }
        __syncthreads();

        #pragma unroll
        for (int k = 0; k < BK; ++k) {
            const float4 ra = *(const float4*)(&As[k][ty * 4]);  // broadcast across tx
            const float4 rb = *(const float4*)(&Bs[k][tx * 4]);  // 2-way bank alias: free
            const float a[4] = {ra.x, ra.y, ra.z, ra.w};
            const float b[4] = {rb.x, rb.y, rb.z, rb.w};
            #pragma unroll
            for (int i = 0; i < 4; ++i)
                #pragma unroll
                for (int j = 0; j < 4; ++j)
                    acc[i][j] += a[i] * b[j];
        }
        __syncthreads();
    }

    // Epilogue: bias, optional q-scale, vectorized store
    #pragma unroll
    for (int i = 0; i < 4; ++i) {
        const int m = m0 + ty * 4 + i;
        const int n = n0 + tx * 4;
        float4 v;
        v.x = acc[i][0] + bias[n + 0];
        v.y = acc[i][1] + bias[n + 1];
        v.z = acc[i][2] + bias[n + 2];
        v.w = acc[i][3] + bias[n + 3];
        if (n < qcols) { v.x *= qscale; v.y *= qscale; v.z *= qscale; v.w *= qscale; }
        *(float4*)(C + (size_t)m * N + n) = v;
    }
}

// One thread owns one (token, head): q, 49 logits, softmax, and the 32-ch
// output accumulator all live in registers. No shuffles, no hot-path syncs.
// Block = 32 consecutive tokens x 8 heads = 256 threads (L1 reuse across the
// overlapping 7x7 neighborhoods of a row segment).
// OOB neighbors (zero-padded k,v in the reference): logit = rpb only, still
// inside the softmax; v contributes nothing.
__global__ __launch_bounds__(256) void na2d_attn2(
    const float* __restrict__ qkv, const float* __restrict__ rpb,
    float* __restrict__ out)
{
    const int tid  = threadIdx.x;
    const int head = tid & 7;
    const int ti   = tid >> 3;                 // 0..31
    const int t    = blockIdx.x * 32 + ti;     // 0..12543
    const int b    = t / 3136;
    const int rem  = t % 3136;
    const int y    = rem / 56;
    const int x    = rem % 56;

    __shared__ float srpb[8 * 49];
    for (int i = tid; i < 8 * 49; i += 256) srpb[i] = rpb[i];
    __syncthreads();
    const float* rp = &srpb[head * 49];

    // q fragment (already scaled by the QKV epilogue)
    const float4* qp = (const float4*)(qkv + (size_t)t * 768 + head * 32);
    float4 q[8];
    #pragma unroll
    for (int j = 0; j < 8; ++j) q[j] = qp[j];

    // ---- 49 logits, register-resident ----
    float logit[49];
    #pragma unroll
    for (int ky = 0; ky < 7; ++ky) {
        const int  yy  = y + ky - 3;
        const bool yok = (yy >= 0) && (yy < 56);
        #pragma unroll
        for (int kx = 0; kx < 7; ++kx) {
            const int kk = ky * 7 + kx;
            const int xx = x + kx - 3;
            float l = rp[kk];
            if (yok && xx >= 0 && xx < 56) {
                const float4* kp = (const float4*)(
                    qkv + (size_t)(b * 3136 + yy * 56 + xx) * 768 + 256 + head * 32);
                float4 a = {0.f, 0.f, 0.f, 0.f};
                #pragma unroll
                for (int j = 0; j < 8; ++j) {
                    const float4 kv = kp[j];
                    a.x += q[j].x * kv.x; a.y += q[j].y * kv.y;
                    a.z += q[j].z * kv.z; a.w += q[j].w * kv.w;
                }
                l += (a.x + a.y) + (a.z + a.w);
            }
            logit[kk] = l;
        }
    }

    // ---- in-thread softmax over 49 ----
    float mx = logit[0];
    #pragma unroll
    for (int kk = 1; kk < 49; ++kk) mx = fmaxf(mx, logit[kk]);
    float s = 0.f;
    #pragma unroll
    for (int kk = 0; kk < 49; ++kk) {
        const float e = __expf(logit[kk] - mx);
        logit[kk] = e;                       // now unnormalized probs
        s += e;
    }
    const float inv = 1.f / s;

    // ---- PV: accumulate unnormalized, scale at store ----
    float4 o[8] = {};
    #pragma unroll
    for (int ky = 0; ky < 7; ++ky) {
        const int  yy  = y + ky - 3;
        const bool yok = (yy >= 0) && (yy < 56);
        #pragma unroll
        for (int kx = 0; kx < 7; ++kx) {
            const int xx = x + kx - 3;
            if (yok && xx >= 0 && xx < 56) {
                const float p = logit[ky * 7 + kx];
                const float4* vp = (const float4*)(
                    qkv + (size_t)(b * 3136 + yy * 56 + xx) * 768 + 512 + head * 32);
                #pragma unroll
                for (int j = 0; j < 8; ++j) {
                    const float4 vv = vp[j];
                    o[j].x += p * vv.x; o[j].y += p * vv.y;
                    o[j].z += p * vv.z; o[j].w += p * vv.w;
                }
            }
        }
    }
    float4* op = (float4*)(out + (size_t)t * 256 + head * 32);
    #pragma unroll
    for (int j = 0; j < 8; ++j) {
        float4 v = o[j];
        v.x *= inv; v.y *= inv; v.z *= inv; v.w *= inv;
        op[j] = v;
    }
}

extern "C" void kernel_launch(void* const* d_in, const int* in_sizes, int n_in,
                              void* d_out, int out_size, void* d_ws, size_t ws_size,
                              hipStream_t stream)
{
    const float* x      = (const float*)d_in[0];   // (4,56,56,256)
    const float* w_qkv  = (const float*)d_in[1];   // (256,768)
    const float* b_qkv  = (const float*)d_in[2];   // (768,)
    const float* rpb    = (const float*)d_in[3];   // (8,49)
    const float* w_proj = (const float*)d_in[4];   // (256,256)
    const float* b_proj = (const float*)d_in[5];   // (256,)
    float* out = (float*)d_out;                    // (4,56,56,256) fp32

    const int M = 12544;                           // 4*56*56
    float* qkv      = (float*)d_ws;                // M*768 floats = 38.5 MB
    float* attn_out = qkv + (size_t)M * 768;       // M*256 floats = 12.8 MB

    const float scale = 0.17677669529663689f;      // 32^-0.5

    // qkv = x @ w_qkv + b_qkv, q columns pre-scaled
    gemm_bias<<<dim3(768 / BN, M / BM), 256, 0, stream>>>(
        x, w_qkv, b_qkv, qkv, M, 768, 256, scale, 256);

    // neighborhood attention: 12544/32 = 392 blocks
    na2d_attn2<<<392, 256, 0, stream>>>(qkv, rpb, attn_out);

    // out = attn_out @ w_proj + b_proj
    gemm_bias<<<dim3(256 / BN, M / BM), 256, 0, stream>>>(
        attn_out, w_proj, b_proj, out, M, 256, 256, 1.f, 0);
}

// Round 3
// 290.548 us; speedup vs baseline: 1.3873x; 1.2612x over previous
//
#include <hip/hip_runtime.h>
#include <hip/hip_bf16.h>

// Shapes (fixed): B=4, H=56, W=56, C=256, NH=8, HD=32, KS=7, PAD=3
// tokens M = 4*56*56 = 12544, QKV N = 768, proj N = 256, K = 256.

using frag_ab = __attribute__((ext_vector_type(8))) short;  // 8 bf16 (4 VGPRs)
using f32x4   = __attribute__((ext_vector_type(4))) float;  // 4 fp32 acc

typedef const __attribute__((address_space(1))) unsigned int* gas_u32;
typedef __attribute__((address_space(3))) unsigned int*       las_u32;

__device__ __forceinline__ void gl_lds16(const void* g, void* l) {
    // async global->LDS DMA, 16 B/lane; LDS dst = wave-uniform base + lane*16
    __builtin_amdgcn_global_load_lds((gas_u32)g, (las_u32)l, 16, 0, 0);
}

// ---------- fp32 -> bf16 elementwise (x) ----------
__global__ __launch_bounds__(256) void cvt_x(
    const float* __restrict__ in, __hip_bfloat16* __restrict__ out, int n4)
{
    const int i = blockIdx.x * 256 + threadIdx.x;   // one float4 per thread
    if (i >= n4) return;
    const float4 v = ((const float4*)in)[i];
    union { ushort4 u; __hip_bfloat16 h[4]; } o;
    o.h[0] = __float2bfloat16(v.x);
    o.h[1] = __float2bfloat16(v.y);
    o.h[2] = __float2bfloat16(v.z);
    o.h[3] = __float2bfloat16(v.w);
    ((ushort4*)out)[i] = o.u;
}

// ---------- weight transpose + convert: in[256][N] fp32 -> out[N][256] bf16 ----------
__global__ __launch_bounds__(256) void cvt_wT(
    const float* __restrict__ in, __hip_bfloat16* __restrict__ out, int N)
{
    const int tid = blockIdx.x * 256 + threadIdx.x;  // over N*256
    const int k = tid & 255;
    const int n = tid >> 8;
    out[tid] = __float2bfloat16(in[k * N + n]);
}

// ---------- bf16 MFMA GEMM: C[M,N] = A[M,256] @ BT[N,256]^T + bias ----------
// 64x64 tile, 4 waves; wave w = quadrant (w>>1, w&1) of 2x2 16x16 frags.
// Staging: each wave DMAs A-block w and BT-block w (16 rows x 32 k, in MFMA
// fragment order: lane l <- row (l&15), k-chunk (l>>4)*8) -> ds_read_b128
// fragment loads are contiguous 16 B/lane (2 lanes/bank: conflict-free).
__global__ __launch_bounds__(256) void gemm_mfma_bt(
    const __hip_bfloat16* __restrict__ A,    // [M][256]
    const __hip_bfloat16* __restrict__ BT,   // [N][256]
    const float* __restrict__ bias,          // [N]
    float* __restrict__ C,                   // [M][N] fp32
    int N, float qscale, int qcols)
{
    constexpr int K = 256;
    __shared__ frag_ab AsB[4][64];   // 4 KB
    __shared__ frag_ab BsB[4][64];   // 4 KB

    const int tid  = threadIdx.x;
    const int lane = tid & 63;
    const int w    = tid >> 6;           // wave 0..3
    const int wm   = w >> 1, wn = w & 1;
    const int m0 = blockIdx.y * 64;
    const int n0 = blockIdx.x * 64;

    // per-lane global staging addresses (fragment-order gather)
    const int arow = m0 + w * 16 + (lane & 15);
    const int nrow = n0 + w * 16 + (lane & 15);
    const int koff = (lane >> 4) * 8;
    const __hip_bfloat16* gA = A  + (size_t)arow * K + koff;
    const __hip_bfloat16* gB = BT + (size_t)nrow * K + koff;
    char* lA = (char*)&AsB[w][0];        // wave-uniform LDS base
    char* lB = (char*)&BsB[w][0];

    f32x4 acc[2][2] = {};

    for (int k0 = 0; k0 < K; k0 += 32) {
        gl_lds16(gA, lA);
        gl_lds16(gB, lB);
        gA += 32; gB += 32;
        __syncthreads();                 // drains vmcnt -> staged data visible
        const frag_ab a0 = AsB[2 * wm + 0][lane];
        const frag_ab a1 = AsB[2 * wm + 1][lane];
        const frag_ab b0 = BsB[2 * wn + 0][lane];
        const frag_ab b1 = BsB[2 * wn + 1][lane];
        acc[0][0] = __builtin_amdgcn_mfma_f32_16x16x32_bf16(a0, b0, acc[0][0], 0, 0, 0);
        acc[0][1] = __builtin_amdgcn_mfma_f32_16x16x32_bf16(a0, b1, acc[0][1], 0, 0, 0);
        acc[1][0] = __builtin_amdgcn_mfma_f32_16x16x32_bf16(a1, b0, acc[1][0], 0, 0, 0);
        acc[1][1] = __builtin_amdgcn_mfma_f32_16x16x32_bf16(a1, b1, acc[1][1], 0, 0, 0);
        __syncthreads();                 // frag reads done before re-staging
    }

    // epilogue: C/D layout col=lane&15 (n), row=(lane>>4)*4+reg (m)  [m89-verified]
    const int rbase = (lane >> 4) * 4;
    const int cbase = lane & 15;
    #pragma unroll
    for (int fi = 0; fi < 2; ++fi) {
        const int rm = m0 + wm * 32 + fi * 16 + rbase;
        #pragma unroll
        for (int fj = 0; fj < 2; ++fj) {
            const int cn = n0 + wn * 32 + fj * 16 + cbase;
            const float bv = bias[cn];
            const float sc = (cn < qcols) ? qscale : 1.0f;
            #pragma unroll
            for (int r = 0; r < 4; ++r)
                C[(size_t)(rm + r) * N + cn] = (acc[fi][fj][r] + bv) * sc;
        }
    }
}

// ---------- neighborhood attention (unchanged structure; bf16 output) ----------
// One thread owns one (token, head); q, logits, softmax, PV acc in registers.
// OOB neighbors (zero-padded k,v): logit = rpb only, still inside softmax.
__global__ __launch_bounds__(256) void na2d_attn2(
    const float* __restrict__ qkv, const float* __restrict__ rpb,
    __hip_bfloat16* __restrict__ out)
{
    const int tid  = threadIdx.x;
    const int head = tid & 7;
    const int ti   = tid >> 3;
    const int t    = blockIdx.x * 32 + ti;
    const int b    = t / 3136;
    const int rem  = t % 3136;
    const int y    = rem / 56;
    const int x    = rem % 56;

    __shared__ float srpb[8 * 49];
    for (int i = tid; i < 8 * 49; i += 256) srpb[i] = rpb[i];
    __syncthreads();
    const float* rp = &srpb[head * 49];

    const float4* qp = (const float4*)(qkv + (size_t)t * 768 + head * 32);
    float4 q[8];
    #pragma unroll
    for (int j = 0; j < 8; ++j) q[j] = qp[j];

    float logit[49];
    #pragma unroll
    for (int ky = 0; ky < 7; ++ky) {
        const int  yy  = y + ky - 3;
        const bool yok = (yy >= 0) && (yy < 56);
        #pragma unroll
        for (int kx = 0; kx < 7; ++kx) {
            const int kk = ky * 7 + kx;
            const int xx = x + kx - 3;
            float l = rp[kk];
            if (yok && xx >= 0 && xx < 56) {
                const float4* kp = (const float4*)(
                    qkv + (size_t)(b * 3136 + yy * 56 + xx) * 768 + 256 + head * 32);
                float4 a = {0.f, 0.f, 0.f, 0.f};
                #pragma unroll
                for (int j = 0; j < 8; ++j) {
                    const float4 kv = kp[j];
                    a.x += q[j].x * kv.x; a.y += q[j].y * kv.y;
                    a.z += q[j].z * kv.z; a.w += q[j].w * kv.w;
                }
                l += (a.x + a.y) + (a.z + a.w);
            }
            logit[kk] = l;
        }
    }

    float mx = logit[0];
    #pragma unroll
    for (int kk = 1; kk < 49; ++kk) mx = fmaxf(mx, logit[kk]);
    float s = 0.f;
    #pragma unroll
    for (int kk = 0; kk < 49; ++kk) {
        const float e = __expf(logit[kk] - mx);
        logit[kk] = e;
        s += e;
    }
    const float inv = 1.f / s;

    float4 o[8] = {};
    #pragma unroll
    for (int ky = 0; ky < 7; ++ky) {
        const int  yy  = y + ky - 3;
        const bool yok = (yy >= 0) && (yy < 56);
        #pragma unroll
        for (int kx = 0; kx < 7; ++kx) {
            const int xx = x + kx - 3;
            if (yok && xx >= 0 && xx < 56) {
                const float p = logit[ky * 7 + kx];
                const float4* vp = (const float4*)(
                    qkv + (size_t)(b * 3136 + yy * 56 + xx) * 768 + 512 + head * 32);
                #pragma unroll
                for (int j = 0; j < 8; ++j) {
                    const float4 vv = vp[j];
                    o[j].x += p * vv.x; o[j].y += p * vv.y;
                    o[j].z += p * vv.z; o[j].w += p * vv.w;
                }
            }
        }
    }

    union { uint4 u[4]; __hip_bfloat16 h[32]; } ob;
    #pragma unroll
    for (int j = 0; j < 8; ++j) {
        ob.h[4 * j + 0] = __float2bfloat16(o[j].x * inv);
        ob.h[4 * j + 1] = __float2bfloat16(o[j].y * inv);
        ob.h[4 * j + 2] = __float2bfloat16(o[j].z * inv);
        ob.h[4 * j + 3] = __float2bfloat16(o[j].w * inv);
    }
    uint4* op = (uint4*)(out + (size_t)t * 256 + head * 32);
    #pragma unroll
    for (int i = 0; i < 4; ++i) op[i] = ob.u[i];
}

extern "C" void kernel_launch(void* const* d_in, const int* in_sizes, int n_in,
                              void* d_out, int out_size, void* d_ws, size_t ws_size,
                              hipStream_t stream)
{
    const float* x      = (const float*)d_in[0];   // (4,56,56,256)
    const float* w_qkv  = (const float*)d_in[1];   // (256,768)
    const float* b_qkv  = (const float*)d_in[2];   // (768,)
    const float* rpb    = (const float*)d_in[3];   // (8,49)
    const float* w_proj = (const float*)d_in[4];   // (256,256)
    const float* b_proj = (const float*)d_in[5];   // (256,)
    float* out = (float*)d_out;                    // (4,56,56,256) fp32

    const int M = 12544;

    char* wsp = (char*)d_ws;
    float* qkv = (float*)wsp;                 wsp += (size_t)M * 768 * 4;  // 38.5 MB fp32
    __hip_bfloat16* xb    = (__hip_bfloat16*)wsp; wsp += (size_t)M * 256 * 2;
    __hip_bfloat16* attnb = (__hip_bfloat16*)wsp; wsp += (size_t)M * 256 * 2;
    __hip_bfloat16* wqkvT = (__hip_bfloat16*)wsp; wsp += (size_t)768 * 256 * 2;
    __hip_bfloat16* wprojT= (__hip_bfloat16*)wsp; wsp += (size_t)256 * 256 * 2;

    const float scale = 0.17677669529663689f;  // 32^-0.5

    // converts (x -> bf16; weights -> transposed bf16)
    cvt_x<<<3136, 256, 0, stream>>>(x, xb, M * 256 / 4);
    cvt_wT<<<768, 256, 0, stream>>>(w_qkv, wqkvT, 768);
    cvt_wT<<<256, 256, 0, stream>>>(w_proj, wprojT, 256);

    // qkv = x @ w_qkv + b_qkv (q cols pre-scaled), fp32 out
    gemm_mfma_bt<<<dim3(768 / 64, M / 64), 256, 0, stream>>>(
        xb, wqkvT, b_qkv, qkv, 768, scale, 256);

    // neighborhood attention -> bf16 (feeds proj GEMM)
    na2d_attn2<<<M / 32, 256, 0, stream>>>(qkv, rpb, attnb);

    // out = attn @ w_proj + b_proj, fp32 out
    gemm_mfma_bt<<<dim3(256 / 64, M / 64), 256, 0, stream>>>(
        attnb, wprojT, b_proj, out, 256, 1.f, 0);
}

// Round 4
// 206.529 us; speedup vs baseline: 1.9516x; 1.4068x over previous
//
#include <hip/hip_runtime.h>
#include <hip/hip_bf16.h>

// Shapes (fixed): B=4, H=56, W=56, C=256, NH=8, HD=32, KS=7, PAD=3
// tokens M = 4*56*56 = 12544, QKV N = 768, proj N = 256, K = 256.

using frag_ab = __attribute__((ext_vector_type(8))) short;  // 8 bf16 (4 VGPRs)
using f32x4   = __attribute__((ext_vector_type(4))) float;  // 4 fp32 acc

typedef const __attribute__((address_space(1))) unsigned int* gas_u32;
typedef __attribute__((address_space(3))) unsigned int*       las_u32;

__device__ __forceinline__ void gl_lds16(const void* g, void* l) {
    __builtin_amdgcn_global_load_lds((gas_u32)g, (las_u32)l, 16, 0, 0);
}

// ---------- fp32 -> bf16 elementwise (x) ----------
__global__ __launch_bounds__(256) void cvt_x(
    const float* __restrict__ in, __hip_bfloat16* __restrict__ out, int n4)
{
    const int i = blockIdx.x * 256 + threadIdx.x;
    if (i >= n4) return;
    const float4 v = ((const float4*)in)[i];
    union { ushort4 u; __hip_bfloat16 h[4]; } o;
    o.h[0] = __float2bfloat16(v.x);
    o.h[1] = __float2bfloat16(v.y);
    o.h[2] = __float2bfloat16(v.z);
    o.h[3] = __float2bfloat16(v.w);
    ((ushort4*)out)[i] = o.u;
}

// ---------- weight transpose + convert: in[256][N] fp32 -> out[N][256] bf16 ----------
__global__ __launch_bounds__(256) void cvt_wT(
    const float* __restrict__ in, __hip_bfloat16* __restrict__ out, int N)
{
    const int tid = blockIdx.x * 256 + threadIdx.x;
    const int k = tid & 255;
    const int n = tid >> 8;
    out[tid] = __float2bfloat16(in[k * N + n]);
}

// ---------- bf16 MFMA GEMM: C[M,N] = A[M,256] @ BT[N,256]^T + bias ----------
__global__ __launch_bounds__(256) void gemm_mfma_bt(
    const __hip_bfloat16* __restrict__ A,
    const __hip_bfloat16* __restrict__ BT,
    const float* __restrict__ bias,
    float* __restrict__ C,
    int N, float qscale, int qcols)
{
    constexpr int K = 256;
    __shared__ frag_ab AsB[4][64];
    __shared__ frag_ab BsB[4][64];

    const int tid  = threadIdx.x;
    const int lane = tid & 63;
    const int w    = tid >> 6;
    const int wm   = w >> 1, wn = w & 1;
    const int m0 = blockIdx.y * 64;
    const int n0 = blockIdx.x * 64;

    const int arow = m0 + w * 16 + (lane & 15);
    const int nrow = n0 + w * 16 + (lane & 15);
    const int koff = (lane >> 4) * 8;
    const __hip_bfloat16* gA = A  + (size_t)arow * K + koff;
    const __hip_bfloat16* gB = BT + (size_t)nrow * K + koff;
    char* lA = (char*)&AsB[w][0];
    char* lB = (char*)&BsB[w][0];

    f32x4 acc[2][2] = {};

    for (int k0 = 0; k0 < K; k0 += 32) {
        gl_lds16(gA, lA);
        gl_lds16(gB, lB);
        gA += 32; gB += 32;
        __syncthreads();
        const frag_ab a0 = AsB[2 * wm + 0][lane];
        const frag_ab a1 = AsB[2 * wm + 1][lane];
        const frag_ab b0 = BsB[2 * wn + 0][lane];
        const frag_ab b1 = BsB[2 * wn + 1][lane];
        acc[0][0] = __builtin_amdgcn_mfma_f32_16x16x32_bf16(a0, b0, acc[0][0], 0, 0, 0);
        acc[0][1] = __builtin_amdgcn_mfma_f32_16x16x32_bf16(a0, b1, acc[0][1], 0, 0, 0);
        acc[1][0] = __builtin_amdgcn_mfma_f32_16x16x32_bf16(a1, b0, acc[1][0], 0, 0, 0);
        acc[1][1] = __builtin_amdgcn_mfma_f32_16x16x32_bf16(a1, b1, acc[1][1], 0, 0, 0);
        __syncthreads();
    }

    const int rbase = (lane >> 4) * 4;
    const int cbase = lane & 15;
    #pragma unroll
    for (int fi = 0; fi < 2; ++fi) {
        const int rm = m0 + wm * 32 + fi * 16 + rbase;
        #pragma unroll
        for (int fj = 0; fj < 2; ++fj) {
            const int cn = n0 + wn * 32 + fj * 16 + cbase;
            const float bv = bias[cn];
            const float sc = (cn < qcols) ? qscale : 1.0f;
            #pragma unroll
            for (int r = 0; r < 4; ++r)
                C[(size_t)(rm + r) * N + cn] = (acc[fi][fj][r] + bv) * sc;
        }
    }
}

// ---------- neighborhood attention, LDS-staged ----------
// Block = 64 threads = 8 tokens (one row segment) x 8 heads. Grid = 1568.
// Per ky: stage 14 cols x 256 ch of the k-row (then v-row) fp32->bf16 into
// LDS, double-buffered. x-OOB cols staged as ZEROS (reference zero-pads), so
// the inner loops are branch-free; y-OOB rows are a block-uniform skip
// (logit stays = rpb, still inside the softmax).
// LDS leading dim padded 256->264 ch: col stride 528 B = 132 words == 4 mod 32
// -> the (token,head) fragment reads spread uniformly over all 32 banks.
__device__ __forceinline__ float bflo(unsigned int u) {
    return __uint_as_float(u << 16);
}
__device__ __forceinline__ float bfhi(unsigned int u) {
    return __uint_as_float(u & 0xffff0000u);
}

__global__ __launch_bounds__(64) void na2d_attn3(
    const float* __restrict__ qkv, const float* __restrict__ rpb,
    __hip_bfloat16* __restrict__ out)
{
    const int tid = threadIdx.x;
    const int h   = tid & 7;          // head
    const int tl  = tid >> 3;         // token within segment 0..7
    const int seg = blockIdx.x;       // 0..1567
    const int row = seg / 7;          // b*56 + y
    const int x0  = (seg % 7) * 8;
    const int y   = row % 56;
    const int t   = row * 56 + x0 + tl;          // global token index
    const int rowtok0 = (row - y) * 56 + ((row / 56) ? 0 : 0); // placeholder (unused)

    __shared__ unsigned short kv[2][14][264];    // 14.4 KB
    __shared__ float srpb[8 * 49];

    for (int i = tid; i < 8 * 49; i += 64) srpb[i] = rpb[i];
    const float* rp = &srpb[h * 49];

    // q: 32 fp32 channels in registers
    float q[32];
    {
        const float4* qp = (const float4*)(qkv + (size_t)t * 768 + h * 32);
        #pragma unroll
        for (int i = 0; i < 8; ++i) {
            const float4 v4 = qp[i];
            q[4 * i + 0] = v4.x; q[4 * i + 1] = v4.y;
            q[4 * i + 2] = v4.z; q[4 * i + 3] = v4.w;
        }
    }

    // stage one row (14 cols x 256 ch) of k (po=256) or v (po=512) into buf bi
    auto stage = [&](int ky, int bi, int po) {
        const int yg = y + ky - 3;
        if (yg < 0 || yg >= 56) return;          // block-uniform
        const int tokbase = (row - y + yg) * 56; // (b*56+yg)*56
        #pragma unroll
        for (int u = 0; u < 7; ++u) {
            const int unit = tid + u * 64;       // 0..447
            const int col  = unit >> 5;          // 0..13
            const int j    = unit & 31;          // 8-ch chunk
            const int xg   = x0 - 3 + col;
            union { unsigned short s[8]; __hip_bfloat16 hh[8]; uint4 v; } pk;
            if (xg >= 0 && xg < 56) {
                const float4* src = (const float4*)(
                    qkv + (size_t)(tokbase + xg) * 768 + po + j * 8);
                const float4 a = src[0];
                const float4 c = src[1];
                pk.hh[0] = __float2bfloat16(a.x); pk.hh[1] = __float2bfloat16(a.y);
                pk.hh[2] = __float2bfloat16(a.z); pk.hh[3] = __float2bfloat16(a.w);
                pk.hh[4] = __float2bfloat16(c.x); pk.hh[5] = __float2bfloat16(c.y);
                pk.hh[6] = __float2bfloat16(c.z); pk.hh[7] = __float2bfloat16(c.w);
            } else {
                pk.v = make_uint4(0u, 0u, 0u, 0u);
            }
            *(uint4*)&kv[bi][col][j * 8] = pk.v;
        }
    };

    float logit[49];
    #pragma unroll
    for (int kk = 0; kk < 49; ++kk) logit[kk] = rp[kk];

    // ---- QK phase ----
    __syncthreads();          // srpb visible (single wave: just a waitcnt)
    stage(0, 0, 256);
    #pragma unroll
    for (int ky = 0; ky < 7; ++ky) {
        __syncthreads();
        if (ky < 6) stage(ky + 1, (ky + 1) & 1, 256);
        const int yg = y + ky - 3;
        if (yg >= 0 && yg < 56) {
            const int bi = ky & 1;
            #pragma unroll
            for (int kx = 0; kx < 7; ++kx) {
                const uint4* p = (const uint4*)&kv[bi][tl + kx][h * 32];
                float s = 0.f;
                #pragma unroll
                for (int qd = 0; qd < 4; ++qd) {
                    const uint4 w = p[qd];
                    const int o8 = qd * 8;
                    s += q[o8 + 0] * bflo(w.x) + q[o8 + 1] * bfhi(w.x)
                       + q[o8 + 2] * bflo(w.y) + q[o8 + 3] * bfhi(w.y)
                       + q[o8 + 4] * bflo(w.z) + q[o8 + 5] * bfhi(w.z)
                       + q[o8 + 6] * bflo(w.w) + q[o8 + 7] * bfhi(w.w);
                }
                logit[ky * 7 + kx] += s;
            }
        }
    }

    // ---- softmax over 49 (in registers) ----
    float mx = logit[0];
    #pragma unroll
    for (int kk = 1; kk < 49; ++kk) mx = fmaxf(mx, logit[kk]);
    float ssum = 0.f;
    #pragma unroll
    for (int kk = 0; kk < 49; ++kk) {
        const float e = __expf(logit[kk] - mx);
        logit[kk] = e;
        ssum += e;
    }
    const float inv = 1.f / ssum;

    // ---- PV phase ----
    float o[32] = {};
    __syncthreads();          // last QK reads done before overwriting buf0
    stage(0, 0, 512);
    #pragma unroll
    for (int ky = 0; ky < 7; ++ky) {
        __syncthreads();
        if (ky < 6) stage(ky + 1, (ky + 1) & 1, 512);
        const int yg = y + ky - 3;
        if (yg >= 0 && yg < 56) {
            const int bi = ky & 1;
            #pragma unroll
            for (int kx = 0; kx < 7; ++kx) {
                const float pr = logit[ky * 7 + kx];
                const uint4* p = (const uint4*)&kv[bi][tl + kx][h * 32];
                #pragma unroll
                for (int qd = 0; qd < 4; ++qd) {
                    const uint4 w = p[qd];
                    const int o8 = qd * 8;
                    o[o8 + 0] += pr * bflo(w.x); o[o8 + 1] += pr * bfhi(w.x);
                    o[o8 + 2] += pr * bflo(w.y); o[o8 + 3] += pr * bfhi(w.y);
                    o[o8 + 4] += pr * bflo(w.z); o[o8 + 5] += pr * bfhi(w.z);
                    o[o8 + 6] += pr * bflo(w.w); o[o8 + 7] += pr * bfhi(w.w);
                }
            }
        }
    }

    // ---- store bf16 (feeds proj GEMM) ----
    union { uint4 u[4]; __hip_bfloat16 hh[32]; } ob;
    #pragma unroll
    for (int i = 0; i < 32; ++i) ob.hh[i] = __float2bfloat16(o[i] * inv);
    uint4* op = (uint4*)(out + (size_t)t * 256 + h * 32);
    #pragma unroll
    for (int i = 0; i < 4; ++i) op[i] = ob.u[i];
}

extern "C" void kernel_launch(void* const* d_in, const int* in_sizes, int n_in,
                              void* d_out, int out_size, void* d_ws, size_t ws_size,
                              hipStream_t stream)
{
    const float* x      = (const float*)d_in[0];   // (4,56,56,256)
    const float* w_qkv  = (const float*)d_in[1];   // (256,768)
    const float* b_qkv  = (const float*)d_in[2];   // (768,)
    const float* rpb    = (const float*)d_in[3];   // (8,49)
    const float* w_proj = (const float*)d_in[4];   // (256,256)
    const float* b_proj = (const float*)d_in[5];   // (256,)
    float* out = (float*)d_out;                    // (4,56,56,256) fp32

    const int M = 12544;

    char* wsp = (char*)d_ws;
    float* qkv = (float*)wsp;                 wsp += (size_t)M * 768 * 4;
    __hip_bfloat16* xb    = (__hip_bfloat16*)wsp; wsp += (size_t)M * 256 * 2;
    __hip_bfloat16* attnb = (__hip_bfloat16*)wsp; wsp += (size_t)M * 256 * 2;
    __hip_bfloat16* wqkvT = (__hip_bfloat16*)wsp; wsp += (size_t)768 * 256 * 2;
    __hip_bfloat16* wprojT= (__hip_bfloat16*)wsp; wsp += (size_t)256 * 256 * 2;

    const float scale = 0.17677669529663689f;  // 32^-0.5

    cvt_x<<<3136, 256, 0, stream>>>(x, xb, M * 256 / 4);
    cvt_wT<<<768, 256, 0, stream>>>(w_qkv, wqkvT, 768);
    cvt_wT<<<256, 256, 0, stream>>>(w_proj, wprojT, 256);

    gemm_mfma_bt<<<dim3(768 / 64, M / 64), 256, 0, stream>>>(
        xb, wqkvT, b_qkv, qkv, 768, scale, 256);

    // attention: 1568 blocks of 64 threads (8 tokens x 8 heads)
    na2d_attn3<<<1568, 64, 0, stream>>>(qkv, rpb, attnb);

    gemm_mfma_bt<<<dim3(256 / 64, M / 64), 256, 0, stream>>>(
        attnb, wprojT, b_proj, out, 256, 1.f, 0);
}

// Round 5
// 187.001 us; speedup vs baseline: 2.1554x; 1.1044x over previous
//
#include <hip/hip_runtime.h>
#include <hip/hip_bf16.h>

// Shapes (fixed): B=4, H=56, W=56, C=256, NH=8, HD=32, KS=7, PAD=3
// tokens M = 4*56*56 = 12544, QKV N = 768, proj N = 256, K = 256.

using frag_ab = __attribute__((ext_vector_type(8))) short;  // 8 bf16 (4 VGPRs)
using f32x4   = __attribute__((ext_vector_type(4))) float;  // 4 fp32 acc

typedef const __attribute__((address_space(1))) unsigned int* gas_u32;
typedef __attribute__((address_space(3))) unsigned int*       las_u32;

__device__ __forceinline__ void gl_lds16(const void* g, void* l) {
    // async global->LDS DMA, 16 B/lane; LDS dst = wave-uniform base + lane*16
    __builtin_amdgcn_global_load_lds((gas_u32)g, (las_u32)l, 16, 0, 0);
}

__device__ __forceinline__ float bflo(unsigned int u) { return __uint_as_float(u << 16); }
__device__ __forceinline__ float bfhi(unsigned int u) { return __uint_as_float(u & 0xffff0000u); }

// ---------- fp32 -> bf16 elementwise (x) ----------
__global__ __launch_bounds__(256) void cvt_x(
    const float* __restrict__ in, __hip_bfloat16* __restrict__ out, int n4)
{
    const int i = blockIdx.x * 256 + threadIdx.x;
    if (i >= n4) return;
    const float4 v = ((const float4*)in)[i];
    union { ushort4 u; __hip_bfloat16 h[4]; } o;
    o.h[0] = __float2bfloat16(v.x);
    o.h[1] = __float2bfloat16(v.y);
    o.h[2] = __float2bfloat16(v.z);
    o.h[3] = __float2bfloat16(v.w);
    ((ushort4*)out)[i] = o.u;
}

// ---------- weight transpose + convert: in[256][N] fp32 -> out[N][256] bf16 ----------
__global__ __launch_bounds__(256) void cvt_wT(
    const float* __restrict__ in, __hip_bfloat16* __restrict__ out, int N)
{
    const int tid = blockIdx.x * 256 + threadIdx.x;
    const int k = tid & 255;
    const int n = tid >> 8;
    out[tid] = __float2bfloat16(in[k * N + n]);
}

// ---------- QKV GEMM with routed epilogue ----------
// C = A[M,256] @ BT[768,256]^T + bias. blockIdx.x: tiles 0-3 -> q (fp32,
// scaled) into qf[M][256]; 4-7 -> k, 8-11 -> v as bf16 into spatially padded
// planes [4][64][64][256] (interior at [y+3][x+3]; pads pre-zeroed).
__global__ __launch_bounds__(256) void gemm_qkv(
    const __hip_bfloat16* __restrict__ A,
    const __hip_bfloat16* __restrict__ BT,
    const float* __restrict__ bias,
    float* __restrict__ qf,
    __hip_bfloat16* __restrict__ kp,
    __hip_bfloat16* __restrict__ vp,
    float qscale)
{
    constexpr int K = 256;
    __shared__ frag_ab AsB[4][64];
    __shared__ frag_ab BsB[4][64];

    const int tid  = threadIdx.x;
    const int lane = tid & 63;
    const int w    = tid >> 6;
    const int wm   = w >> 1, wn = w & 1;
    const int m0 = blockIdx.y * 64;
    const int n0 = blockIdx.x * 64;

    const int arow = m0 + w * 16 + (lane & 15);
    const int nrow = n0 + w * 16 + (lane & 15);
    const int koff = (lane >> 4) * 8;
    const __hip_bfloat16* gA = A  + (size_t)arow * K + koff;
    const __hip_bfloat16* gB = BT + (size_t)nrow * K + koff;
    char* lA = (char*)&AsB[w][0];
    char* lB = (char*)&BsB[w][0];

    f32x4 acc[2][2] = {};

    for (int k0 = 0; k0 < K; k0 += 32) {
        gl_lds16(gA, lA);
        gl_lds16(gB, lB);
        gA += 32; gB += 32;
        __syncthreads();
        const frag_ab a0 = AsB[2 * wm + 0][lane];
        const frag_ab a1 = AsB[2 * wm + 1][lane];
        const frag_ab b0 = BsB[2 * wn + 0][lane];
        const frag_ab b1 = BsB[2 * wn + 1][lane];
        acc[0][0] = __builtin_amdgcn_mfma_f32_16x16x32_bf16(a0, b0, acc[0][0], 0, 0, 0);
        acc[0][1] = __builtin_amdgcn_mfma_f32_16x16x32_bf16(a0, b1, acc[0][1], 0, 0, 0);
        acc[1][0] = __builtin_amdgcn_mfma_f32_16x16x32_bf16(a1, b0, acc[1][0], 0, 0, 0);
        acc[1][1] = __builtin_amdgcn_mfma_f32_16x16x32_bf16(a1, b1, acc[1][1], 0, 0, 0);
        __syncthreads();
    }

    const int rbase = (lane >> 4) * 4;
    const int cbase = lane & 15;
    const int sel   = blockIdx.x >> 2;          // 0=q, 1=k, 2=v (block-uniform)
    __hip_bfloat16* dst = (sel == 1) ? kp : vp;
    #pragma unroll
    for (int fi = 0; fi < 2; ++fi) {
        const int rm = m0 + wm * 32 + fi * 16 + rbase;
        #pragma unroll
        for (int fj = 0; fj < 2; ++fj) {
            const int cn = n0 + wn * 32 + fj * 16 + cbase;
            const float bv = bias[cn];
            #pragma unroll
            for (int r = 0; r < 4; ++r) {
                const int m = rm + r;
                const float val = acc[fi][fj][r] + bv;
                if (sel == 0) {
                    qf[(size_t)m * 256 + cn] = val * qscale;
                } else {
                    const int c  = cn & 255;
                    const int b  = m / 3136;
                    const int r2 = m % 3136;
                    const int yy = r2 / 56;
                    const int xx = r2 % 56;
                    dst[(((size_t)(b * 64 + yy + 3)) * 64 + (xx + 3)) * 256 + c] =
                        __float2bfloat16(val);
                }
            }
        }
    }
}

// ---------- generic MFMA GEMM (proj): C fp32 = A bf16 @ BT bf16 + bias ----------
__global__ __launch_bounds__(256) void gemm_mfma_bt(
    const __hip_bfloat16* __restrict__ A,
    const __hip_bfloat16* __restrict__ BT,
    const float* __restrict__ bias,
    float* __restrict__ C,
    int N)
{
    constexpr int K = 256;
    __shared__ frag_ab AsB[4][64];
    __shared__ frag_ab BsB[4][64];

    const int tid  = threadIdx.x;
    const int lane = tid & 63;
    const int w    = tid >> 6;
    const int wm   = w >> 1, wn = w & 1;
    const int m0 = blockIdx.y * 64;
    const int n0 = blockIdx.x * 64;

    const int arow = m0 + w * 16 + (lane & 15);
    const int nrow = n0 + w * 16 + (lane & 15);
    const int koff = (lane >> 4) * 8;
    const __hip_bfloat16* gA = A  + (size_t)arow * K + koff;
    const __hip_bfloat16* gB = BT + (size_t)nrow * K + koff;
    char* lA = (char*)&AsB[w][0];
    char* lB = (char*)&BsB[w][0];

    f32x4 acc[2][2] = {};

    for (int k0 = 0; k0 < K; k0 += 32) {
        gl_lds16(gA, lA);
        gl_lds16(gB, lB);
        gA += 32; gB += 32;
        __syncthreads();
        const frag_ab a0 = AsB[2 * wm + 0][lane];
        const frag_ab a1 = AsB[2 * wm + 1][lane];
        const frag_ab b0 = BsB[2 * wn + 0][lane];
        const frag_ab b1 = BsB[2 * wn + 1][lane];
        acc[0][0] = __builtin_amdgcn_mfma_f32_16x16x32_bf16(a0, b0, acc[0][0], 0, 0, 0);
        acc[0][1] = __builtin_amdgcn_mfma_f32_16x16x32_bf16(a0, b1, acc[0][1], 0, 0, 0);
        acc[1][0] = __builtin_amdgcn_mfma_f32_16x16x32_bf16(a1, b0, acc[1][0], 0, 0, 0);
        acc[1][1] = __builtin_amdgcn_mfma_f32_16x16x32_bf16(a1, b1, acc[1][1], 0, 0, 0);
        __syncthreads();
    }

    const int rbase = (lane >> 4) * 4;
    const int cbase = lane & 15;
    #pragma unroll
    for (int fi = 0; fi < 2; ++fi) {
        const int rm = m0 + wm * 32 + fi * 16 + rbase;
        #pragma unroll
        for (int fj = 0; fj < 2; ++fj) {
            const int cn = n0 + wn * 32 + fj * 16 + cbase;
            const float bv = bias[cn];
            #pragma unroll
            for (int r = 0; r < 4; ++r)
                C[(size_t)(rm + r) * N + cn] = acc[fi][fj][r] + bv;
        }
    }
}

// ---------- neighborhood attention, DMA-staged, barrier-free hot loop ----------
// Block = 128 thr = 2 INDEPENDENT waves. Wave = 4 tokens x 8 heads x 2 half-heads.
// Grid = 1568 (12544/8 tokens). Per ky the wave DMAs a contiguous 10-col x 256-ch
// bf16 row segment from the padded k (then v) plane into its private LDS buffer,
// double-buffered with manual s_waitcnt vmcnt(5) (own-wave DMAs only -> no
// barrier, no full drain). Zero-padded planes make everything branch-free.
__global__ __launch_bounds__(128) void na2d_attn4(
    const float* __restrict__ qf,
    const __hip_bfloat16* __restrict__ kp,
    const __hip_bfloat16* __restrict__ vp,
    const float* __restrict__ rpb,
    __hip_bfloat16* __restrict__ out)
{
    const int tid  = threadIdx.x;
    const int wave = tid >> 6;
    const int lane = tid & 63;
    const int half = lane & 1;          // 16-ch half of a head
    const int h    = (lane >> 1) & 7;   // head
    const int tl   = (lane >> 4) & 3;   // token within wave's 4-token segment

    const int seg = blockIdx.x;         // 0..1567 : 8-token segment
    const int row = seg / 7;            // b*56 + y
    const int x0  = (seg % 7) * 8 + wave * 4;   // wave's segment start (0..52)
    const int b   = row / 56;
    const int y   = row % 56;
    const int t   = row * 56 + x0 + tl;
    const int prow0 = b * 64 + y;       // padded plane row for ky=0 (y+ky in [0,61])

    __shared__ __hip_bfloat16 kbuf[2][2][2560];   // [wave][parity][10 cols * 256 ch] = 20 KB
    __shared__ float srpb[8 * 49];

    for (int i = tid; i < 8 * 49; i += 128) srpb[i] = rpb[i];
    __syncthreads();                    // only sync in the kernel

    // q: 16 fp32 channels (coalesced: lanes 0..15 cover one token's 256 ch)
    float q[16];
    {
        const float4* qp = (const float4*)(qf + (size_t)t * 256 + h * 32 + half * 16);
        #pragma unroll
        for (int i = 0; i < 4; ++i) {
            const float4 v4 = qp[i];
            q[4 * i + 0] = v4.x; q[4 * i + 1] = v4.y;
            q[4 * i + 2] = v4.z; q[4 * i + 3] = v4.w;
        }
    }

    // DMA one padded row segment (10 cols x 256 ch bf16 = 5 KB, contiguous)
    auto stage = [&](const __hip_bfloat16* plane, int ky) {
        const __hip_bfloat16* rb = plane + ((size_t)(prow0 + ky) * 64 + x0) * 256;
        char* lb = (char*)&kbuf[wave][ky & 1][0];
        #pragma unroll
        for (int i = 0; i < 5; ++i)
            gl_lds16(rb + i * 512 + lane * 8, lb + i * 1024);
    };

    float logit[49];

    // ---- QK phase ----
    auto qk_row = [&](int ky) {
        const __hip_bfloat16* kb = &kbuf[wave][ky & 1][0];
        #pragma unroll
        for (int kx = 0; kx < 7; ++kx) {
            const uint4* p = (const uint4*)(kb + (tl + kx) * 256 + h * 32 + half * 16);
            float s = 0.f;
            #pragma unroll
            for (int qd = 0; qd < 2; ++qd) {
                const uint4 wv = p[qd];
                const int o8 = qd * 8;
                s += q[o8 + 0] * bflo(wv.x) + q[o8 + 1] * bfhi(wv.x)
                   + q[o8 + 2] * bflo(wv.y) + q[o8 + 3] * bfhi(wv.y)
                   + q[o8 + 4] * bflo(wv.z) + q[o8 + 5] * bfhi(wv.z)
                   + q[o8 + 6] * bflo(wv.w) + q[o8 + 7] * bfhi(wv.w);
            }
            logit[ky * 7 + kx] = s;
        }
    };

    stage(kp, 0); stage(kp, 1);
    #pragma unroll
    for (int ky = 0; ky < 6; ++ky) {
        __builtin_amdgcn_sched_barrier(0);
        __builtin_amdgcn_s_waitcnt(0x75);   // vmcnt<=5 (next buf in flight), lgkm 0
        __builtin_amdgcn_sched_barrier(0);
        qk_row(ky);
        __builtin_amdgcn_sched_barrier(0);
        if (ky < 5) stage(kp, ky + 2);
    }
    __builtin_amdgcn_sched_barrier(0);
    __builtin_amdgcn_s_waitcnt(0x70);       // last row: vmcnt 0
    __builtin_amdgcn_sched_barrier(0);
    qk_row(6);

    // merge half-head partial dots (lane pairs differ only in `half`)
    #pragma unroll
    for (int kk = 0; kk < 49; ++kk)
        logit[kk] += __shfl_xor(logit[kk], 1, 64);

    // ---- softmax over 49 (+rpb; zero-pad rows/cols give logit = rpb) ----
    const float* rp = &srpb[h * 49];
    float mx = -1e30f;
    #pragma unroll
    for (int kk = 0; kk < 49; ++kk) {
        logit[kk] += rp[kk];
        mx = fmaxf(mx, logit[kk]);
    }
    float ssum = 0.f;
    #pragma unroll
    for (int kk = 0; kk < 49; ++kk) {
        const float e = __expf(logit[kk] - mx);
        logit[kk] = e;
        ssum += e;
    }
    const float inv = 1.f / ssum;

    // ---- PV phase ----
    float o[16] = {};
    auto pv_row = [&](int ky) {
        const __hip_bfloat16* vb = &kbuf[wave][ky & 1][0];
        #pragma unroll
        for (int kx = 0; kx < 7; ++kx) {
            const float pr = logit[ky * 7 + kx];
            const uint4* p = (const uint4*)(vb + (tl + kx) * 256 + h * 32 + half * 16);
            #pragma unroll
            for (int qd = 0; qd < 2; ++qd) {
                const uint4 wv = p[qd];
                const int o8 = qd * 8;
                o[o8 + 0] += pr * bflo(wv.x); o[o8 + 1] += pr * bfhi(wv.x);
                o[o8 + 2] += pr * bflo(wv.y); o[o8 + 3] += pr * bfhi(wv.y);
                o[o8 + 4] += pr * bflo(wv.z); o[o8 + 5] += pr * bfhi(wv.z);
                o[o8 + 6] += pr * bflo(wv.w); o[o8 + 7] += pr * bfhi(wv.w);
            }
        }
    };

    __builtin_amdgcn_sched_barrier(0);
    stage(vp, 0); stage(vp, 1);
    #pragma unroll
    for (int ky = 0; ky < 6; ++ky) {
        __builtin_amdgcn_sched_barrier(0);
        __builtin_amdgcn_s_waitcnt(0x75);
        __builtin_amdgcn_sched_barrier(0);
        pv_row(ky);
        __builtin_amdgcn_sched_barrier(0);
        if (ky < 5) stage(vp, ky + 2);
    }
    __builtin_amdgcn_sched_barrier(0);
    __builtin_amdgcn_s_waitcnt(0x70);
    __builtin_amdgcn_sched_barrier(0);
    pv_row(6);

    // ---- store bf16 (feeds proj GEMM) ----
    union { uint4 u[2]; __hip_bfloat16 hh[16]; } ob;
    #pragma unroll
    for (int i = 0; i < 16; ++i) ob.hh[i] = __float2bfloat16(o[i] * inv);
    uint4* op = (uint4*)(out + (size_t)t * 256 + h * 32 + half * 16);
    op[0] = ob.u[0];
    op[1] = ob.u[1];
}

extern "C" void kernel_launch(void* const* d_in, const int* in_sizes, int n_in,
                              void* d_out, int out_size, void* d_ws, size_t ws_size,
                              hipStream_t stream)
{
    const float* x      = (const float*)d_in[0];   // (4,56,56,256)
    const float* w_qkv  = (const float*)d_in[1];   // (256,768)
    const float* b_qkv  = (const float*)d_in[2];   // (768,)
    const float* rpb    = (const float*)d_in[3];   // (8,49)
    const float* w_proj = (const float*)d_in[4];   // (256,256)
    const float* b_proj = (const float*)d_in[5];   // (256,)
    float* out = (float*)d_out;                    // (4,56,56,256) fp32

    const int M = 12544;

    char* wsp = (char*)d_ws;
    float* qf = (float*)wsp;                      wsp += (size_t)M * 256 * 4;   // 12.85 MB
    __hip_bfloat16* kp    = (__hip_bfloat16*)wsp; wsp += (size_t)4 * 64 * 64 * 256 * 2; // 8.39 MB
    __hip_bfloat16* vp    = (__hip_bfloat16*)wsp; wsp += (size_t)4 * 64 * 64 * 256 * 2; // 8.39 MB
    __hip_bfloat16* xb    = (__hip_bfloat16*)wsp; wsp += (size_t)M * 256 * 2;
    __hip_bfloat16* attnb = (__hip_bfloat16*)wsp; wsp += (size_t)M * 256 * 2;
    __hip_bfloat16* wqkvT = (__hip_bfloat16*)wsp; wsp += (size_t)768 * 256 * 2;
    __hip_bfloat16* wprojT= (__hip_bfloat16*)wsp; wsp += (size_t)256 * 256 * 2;

    const float scale = 0.17677669529663689f;  // 32^-0.5

    // zero the padded k/v planes (kp,vp adjacent -> one memset, 16.8 MB)
    hipMemsetAsync(kp, 0, (size_t)2 * 4 * 64 * 64 * 256 * 2, stream);

    cvt_x<<<3136, 256, 0, stream>>>(x, xb, M * 256 / 4);
    cvt_wT<<<768, 256, 0, stream>>>(w_qkv, wqkvT, 768);
    cvt_wT<<<256, 256, 0, stream>>>(w_proj, wprojT, 256);

    // qkv GEMM with routed epilogue (q fp32 scaled; k,v bf16 into padded planes)
    gemm_qkv<<<dim3(12, M / 64), 256, 0, stream>>>(
        xb, wqkvT, b_qkv, qf, kp, vp, scale);

    // attention: 1568 blocks x 128 threads (2 independent waves of 4 tokens)
    na2d_attn4<<<1568, 128, 0, stream>>>(qf, kp, vp, rpb, attnb);

    // out = attn @ w_proj + b_proj
    gemm_mfma_bt<<<dim3(256 / 64, M / 64), 256, 0, stream>>>(
        attnb, wprojT, b_proj, out, 256);
}